// Round 11
// baseline (221.085 us; speedup 1.0000x reference)
//
#include <hip/hip_runtime.h>
#include <hip/hip_bf16.h>

#define MM 16384
#define NN 4096
#define KK 512

typedef __bf16 bf16x8 __attribute__((ext_vector_type(8)));
typedef float  f32x16 __attribute__((ext_vector_type(16)));

// ---------------------------------------------------------------------------
// prep_x: x_sq[row] = ||X[row]||^2 (f32), Xb = bf16(X)
// ---------------------------------------------------------------------------
__global__ __launch_bounds__(256) void prep_x_kernel(
    const float* __restrict__ X,
    __bf16* __restrict__ Xb, float* __restrict__ x_sq)
{
    int row  = blockIdx.x * 4 + (threadIdx.x >> 6);
    int lane = threadIdx.x & 63;
    const float4* src = (const float4*)(X + (size_t)row * KK) + lane * 2;
    float4 a = src[0];
    float4 b = src[1];
    float s = a.x*a.x + a.y*a.y + a.z*a.z + a.w*a.w
            + b.x*b.x + b.y*b.y + b.z*b.z + b.w*b.w;
    bf16x8 v;
    v[0]=(__bf16)a.x; v[1]=(__bf16)a.y; v[2]=(__bf16)a.z; v[3]=(__bf16)a.w;
    v[4]=(__bf16)b.x; v[5]=(__bf16)b.y; v[6]=(__bf16)b.z; v[7]=(__bf16)b.w;
    *(bf16x8*)(Xb + (size_t)row * KK + lane * 8) = v;
    #pragma unroll
    for (int o = 1; o < 64; o <<= 1) s += __shfl_xor(s, o);
    if (lane == 0) x_sq[row] = s;
}

// ---------------------------------------------------------------------------
// prep_zt: transpose+convert Z -> Zt AND per-k-block z_sq partials (no atomics)
// ---------------------------------------------------------------------------
__global__ __launch_bounds__(256) void prep_zt_kernel(
    const float* __restrict__ Z, __bf16* __restrict__ Zt,
    float* __restrict__ zsq_part)
{
    __shared__ float t[64][65];
    const int n0 = blockIdx.x * 64;   // 64 blocks
    const int k0 = blockIdx.y * 64;   // 8 blocks
    const int tid = threadIdx.x;
    const int j = tid & 63, i0 = tid >> 6;
    #pragma unroll
    for (int p = 0; p < 16; ++p) {
        int i = i0 * 16 + p;
        t[i][j] = Z[(size_t)(k0 + i) * NN + n0 + j];
    }
    __syncthreads();
    const int nl = tid >> 2, kc = tid & 3;
    bf16x8 v0, v1;
    float s = 0.0f;
    #pragma unroll
    for (int e = 0; e < 8; ++e) {
        float x = t[kc * 16 + e][nl];
        v0[e] = (__bf16)x; s += x * x;
    }
    #pragma unroll
    for (int e = 0; e < 8; ++e) {
        float x = t[kc * 16 + 8 + e][nl];
        v1[e] = (__bf16)x; s += x * x;
    }
    __bf16* dst = Zt + (size_t)(n0 + nl) * KK + k0 + kc * 16;
    *(bf16x8*)(dst)     = v0;
    *(bf16x8*)(dst + 8) = v1;
    s += __shfl_xor(s, 1);
    s += __shfl_xor(s, 2);
    if (kc == 0) zsq_part[blockIdx.y * NN + n0 + nl] = s;
}

// ---------------------------------------------------------------------------
// fused bf16 GEMM 256x256 tile, BK=64, 8 waves (2M x 4N), 128x64 C per wave,
// mfma_f32_32x32x16_bf16 (M_rep=4, N_rep=2, K_rep=4; acc f32x16[4][2]).
// 2-buffer LDS (128KB), stage(t+1) issued at tile start (T3 minimum recipe),
// vmcnt(0)+barrier once per tile (m97-proven drain). Swizzle for 128B rows:
// 16B-granule slot = g ^ (row&7), applied to pre-swizzled global source AND
// ds_read address (rule 21). Bank-audited: 8 dwords/bank/read = floor.
// Epilogue: RBF + in-LDS cross-wave reduce -> deterministic partial store.
// ---------------------------------------------------------------------------
__global__ __launch_bounds__(512) void rbfn_kernel(
    const __bf16* __restrict__ Xb, const __bf16* __restrict__ Zt,
    const float* __restrict__ x_sq, const float* __restrict__ zsq_part,
    const float* __restrict__ beta, const float* __restrict__ log_gamma,
    float* __restrict__ partial)
{
    __shared__ __bf16 As2[2][256 * 64];   // 2 x 32KB
    __shared__ __bf16 Bs2[2][256 * 64];   // 2 x 32KB

    const int tid  = threadIdx.x;
    const int wid  = tid >> 6;          // 0..7
    const int lane = tid & 63;
    const int wr   = wid >> 2;          // 0..1  (M half: 128 rows)
    const int wcn  = wid & 3;           // 0..3  (N quarter: 64 cols)
    const int bx   = blockIdx.x;
    const int cxt  = (bx & 7) * 8 + (bx >> 3);   // XCD-bijective (64 % 8 == 0)
    const int cy   = blockIdx.y;
    const int row0 = cxt * 256;
    const int col0 = cy * 256;

    const int l31 = lane & 31;
    const int l7  = lane & 7;
    const int hi  = lane >> 5;          // 0/1

    // staging: wave wid owns rows [wid*32, wid*32+32). Load i covers rows
    // wid*32+i*8 + (lane>>3), granule slot p = lane&7; stored element must be
    // global granule g = p ^ (row&7) = (lane&7) ^ (lane>>3).
    const __bf16* Ab = Xb + (size_t)(row0 + wid * 32 + (lane >> 3)) * KK
                          + (((lane & 7) ^ (lane >> 3)) * 8);
    const __bf16* Bb = Zt + (size_t)(col0 + wid * 32 + (lane >> 3)) * KK
                          + (((lane & 7) ^ (lane >> 3)) * 8);

#define GLDS(gp, lp) __builtin_amdgcn_global_load_lds( \
        (const __attribute__((address_space(1))) void*)(gp), \
        (__attribute__((address_space(3))) void*)(lp), 16, 0, 0)
#define STAGE_A(kt, b) do { \
        GLDS(Ab + (size_t)(kt) * 64,            &As2[b][wid * 2048]); \
        GLDS(Ab + (size_t)(kt) * 64 +  8 * KK,  &As2[b][wid * 2048 +  512]); \
        GLDS(Ab + (size_t)(kt) * 64 + 16 * KK,  &As2[b][wid * 2048 + 1024]); \
        GLDS(Ab + (size_t)(kt) * 64 + 24 * KK,  &As2[b][wid * 2048 + 1536]); } while (0)
#define STAGE_B(kt, b) do { \
        GLDS(Bb + (size_t)(kt) * 64,            &Bs2[b][wid * 2048]); \
        GLDS(Bb + (size_t)(kt) * 64 +  8 * KK,  &Bs2[b][wid * 2048 +  512]); \
        GLDS(Bb + (size_t)(kt) * 64 + 16 * KK,  &Bs2[b][wid * 2048 + 1024]); \
        GLDS(Bb + (size_t)(kt) * 64 + 24 * KK,  &Bs2[b][wid * 2048 + 1536]); } while (0)

    f32x16 acc[4][2] = {};

    // prologue: stage tile 0, drain, barrier
    STAGE_A(0, 0); STAGE_B(0, 0);
    asm volatile("s_waitcnt vmcnt(0)" ::: "memory");
    __builtin_amdgcn_s_barrier();

    #pragma unroll
    for (int t = 0; t < 8; ++t) {
        const int cur = t & 1;
        const char* curA = (const char*)As2[cur];
        const char* curB = (const char*)Bs2[cur];

        // stage next tile FIRST: HBM latency hides under this tile's compute.
        // buffer cur^1's readers all finished before the end-of-(t-1) barrier.
        if (t < 7) { STAGE_A(t + 1, cur ^ 1); STAGE_B(t + 1, cur ^ 1); }

        // B fragments for the whole tile (reused across all 4 quadrants)
        bf16x8 bfv[2][4];
        #pragma unroll
        for (int ni = 0; ni < 2; ++ni)
            #pragma unroll
            for (int ks = 0; ks < 4; ++ks) {
                const int rb  = wcn * 64 + ni * 32 + l31;
                const int off = rb * 128 + ((((2 * ks + hi)) ^ (rb & 7)) << 4);
                bfv[ni][ks] = *(const bf16x8*)(curB + off);
            }

        // 4 quadrants of 32 rows; compiler pipelines next quadrant's reads
        // under the current quadrant's MFMAs (no barriers in between).
        #pragma unroll
        for (int mi = 0; mi < 4; ++mi) {
            bf16x8 af[4];
            #pragma unroll
            for (int ks = 0; ks < 4; ++ks) {
                const int rr  = wr * 128 + mi * 32 + l31;
                const int off = rr * 128 + ((((2 * ks + hi)) ^ (rr & 7)) << 4);
                af[ks] = *(const bf16x8*)(curA + off);
            }
            __builtin_amdgcn_s_setprio(1);
            #pragma unroll
            for (int ni = 0; ni < 2; ++ni)
                #pragma unroll
                for (int ks = 0; ks < 4; ++ks)
                    acc[mi][ni] = __builtin_amdgcn_mfma_f32_32x32x16_bf16(
                        af[ks], bfv[ni][ks], acc[mi][ni], 0, 0, 0);
            __builtin_amdgcn_s_setprio(0);
        }

        // next tile's loads were issued ~a full tile ago -> drain is cheap
        if (t < 7) asm volatile("s_waitcnt vmcnt(0)" ::: "memory");
        __builtin_amdgcn_s_barrier();
    }
#undef STAGE_A
#undef STAGE_B
#undef GLDS

    // ---- fused RBF epilogue (no global atomics) --------------------------
    // C/D layout (m74/m101): col = lane&31, row = (reg&3) + 8*(reg>>2) + 4*hi
    const float gamma = __expf(log_gamma[0]);
    const float c2    = gamma * 1.4426950408889634f;
    const float twoc2 = 2.0f * c2;

    float czn[2], bet[2];
    #pragma unroll
    for (int ni = 0; ni < 2; ++ni) {
        const int c = col0 + wcn * 64 + ni * 32 + l31;
        float zs = 0.0f;
        #pragma unroll
        for (int q = 0; q < 8; ++q) zs += zsq_part[q * NN + c];
        czn[ni] = -c2 * zs;
        bet[ni] = beta[c];
    }

    float* red = (float*)&As2[0][0];      // [2 wr][4 wcn][128 rows] = 4KB
    #pragma unroll
    for (int mi = 0; mi < 4; ++mi) {
        #pragma unroll
        for (int reg = 0; reg < 16; ++reg) {
            const int rl = (reg & 3) + 8 * (reg >> 2) + 4 * hi;   // 0..31
            const int rloc = mi * 32 + rl;                        // 0..127
            const float cx = -c2 * x_sq[row0 + wr * 128 + rloc];
            float p = 0.0f;
            #pragma unroll
            for (int ni = 0; ni < 2; ++ni) {
                const float arg = fmaf(twoc2, acc[mi][ni][reg], cx + czn[ni]);
                p = fmaf(exp2f(arg), bet[ni], p);
            }
            p += __shfl_xor(p, 1);
            p += __shfl_xor(p, 2);
            p += __shfl_xor(p, 4);
            p += __shfl_xor(p, 8);
            p += __shfl_xor(p, 16);
            if (l31 == 0) red[(wr * 4 + wcn) * 128 + rloc] = p;
        }
    }
    __syncthreads();
    if (tid < 256) {
        const int w = tid >> 7, rloc = tid & 127;
        float s = red[(w * 4 + 0) * 128 + rloc] + red[(w * 4 + 1) * 128 + rloc]
                + red[(w * 4 + 2) * 128 + rloc] + red[(w * 4 + 3) * 128 + rloc];
        partial[(size_t)cy * MM + row0 + tid] = s;
    }
}

// ---------------------------------------------------------------------------
// reduce: out[r] = alpha + sum_{cy} partial[cy][r]
// ---------------------------------------------------------------------------
__global__ __launch_bounds__(256) void reduce_kernel(
    const float* __restrict__ partial, const float* __restrict__ alpha,
    float* __restrict__ out)
{
    const int r = blockIdx.x * 256 + threadIdx.x;
    float s = alpha[0];
    #pragma unroll
    for (int q = 0; q < 16; ++q) s += partial[(size_t)q * MM + r];
    out[r] = s;
}

// ---------------------------------------------------------------------------
extern "C" void kernel_launch(void* const* d_in, const int* in_sizes, int n_in,
                              void* d_out, int out_size, void* d_ws, size_t ws_size,
                              hipStream_t stream) {
    const float* X         = (const float*)d_in[0];
    const float* alpha     = (const float*)d_in[1];
    const float* log_gamma = (const float*)d_in[2];
    const float* beta      = (const float*)d_in[3];
    const float* Z         = (const float*)d_in[4];

    char* ws = (char*)d_ws;
    __bf16* Xb       = (__bf16*)(ws);                   // 16 MB
    __bf16* Zt       = (__bf16*)(ws + 16777216);        //  4 MB
    float*  x_sq     = (float*) (ws + 20971520);        // 64 KB
    float*  zsq_part = (float*) (ws + 21037056);        // 128 KB (8 x 4096)
    float*  partial  = (float*) (ws + 21168128);        // 1 MB  (16 x 16384)
    float*  out      = (float*)d_out;

    prep_x_kernel <<<4096, 256, 0, stream>>>(X, Xb, x_sq);
    prep_zt_kernel<<<dim3(64, 8), 256, 0, stream>>>(Z, Zt, zsq_part);
    rbfn_kernel   <<<dim3(64, 16), 512, 0, stream>>>(Xb, Zt, x_sq, zsq_part,
                                                     beta, log_gamma, partial);
    reduce_kernel <<<64, 256, 0, stream>>>(partial, alpha, out);
}